// Round 1
// baseline (214.376 us; speedup 1.0000x reference)
//
#include <hip/hip_runtime.h>

// BioNorm: out = w * x^p / (sigma^p + depthwise_conv5x5(x^p, edge-pad)) + b
// B=32, C=64, H=W=112, K=5. fp32 throughout. Memory-bound (~206 MB min traffic).
//
// Tiling: one block = one (b, c, 28-row tile). LDS holds 32 rows x 112 cols of
// x^p (stride 116: float4-aligned + breaks pow2 bank stride). Each thread
// computes 4 consecutive outputs per iteration -> row segments of 8 floats
// (even-aligned, ds_read_b64/b128-able) instead of 25 scalar LDS reads/output.
// Edge replicate-pad == clamped window CENTER: cr=clamp(r,2,109),
// cw=clamp(w,2,109); window always reads real rows/cols.

#define Cch 64
#define Hh 112
#define Ww 112
#define TH 28          // output rows per tile (112 = 4*28 exactly)
#define LROWS (TH + 4) // 32 staged rows
#define ST 116         // LDS row stride in floats

__global__ __launch_bounds__(256) void bionorm_kernel(
    const float* __restrict__ x, const float* __restrict__ sigma,
    const float* __restrict__ pow_p, const float* __restrict__ sum_kernel,
    const float* __restrict__ weight, const float* __restrict__ bias,
    float* __restrict__ out)
{
    __shared__ float lds[LROWS * ST];

    const int rt  = blockIdx.x;   // row tile 0..3
    const int c   = blockIdx.y;
    const int b   = blockIdx.z;
    const int tid = threadIdx.x;
    const int r0  = rt * TH;

    // per-channel params (wave-uniform)
    const float p  = pow_p[c];
    const float sg = sigma[c];
    const float wc = weight[c];
    const float bc = bias[c];
    const bool  p2 = (p == 2.0f);
    const float sp = p2 ? sg * sg : __powf(sg, p);

    float kw[25];
    const float* kp = sum_kernel + c * 25;
    #pragma unroll
    for (int j = 0; j < 25; ++j) kw[j] = kp[j];

    const float* xplane = x + ((size_t)(b * Cch + c)) * Hh * Ww;

    // ---- stage x^p tile: 32 rows x 28 float4 ----
    for (int i = tid; i < LROWS * 28; i += 256) {
        int s = i / 28, q = i - s * 28;
        int g = r0 - 2 + s;
        g = g < 0 ? 0 : (g > 111 ? 111 : g);
        const float4 v = *(const float4*)(xplane + g * Ww + q * 4);
        float4 xp;
        if (p2) {
            xp.x = v.x * v.x; xp.y = v.y * v.y;
            xp.z = v.z * v.z; xp.w = v.w * v.w;
        } else {
            xp.x = __powf(v.x, p); xp.y = __powf(v.y, p);
            xp.z = __powf(v.z, p); xp.w = __powf(v.w, p);
        }
        *(float4*)(&lds[s * ST + q * 4]) = xp;
    }
    __syncthreads();

    float* oplane = out + ((size_t)(b * Cch + c)) * Hh * Ww;

    // ---- compute: 28 rows x 28 groups of 4 outputs ----
    for (int i = tid; i < TH * 28; i += 256) {
        int lr = i / 28, gq = i - lr * 28;
        int r  = r0 + lr;
        int w0 = gq * 4;

        int cr    = r  < 2 ? 2 : (r  > 109 ? 109 : r);
        int cwmin = w0 < 2 ? 2 : (w0 > 109 ? 109 : w0);
        int base  = cwmin - 2;      // always even -> 8B-aligned LDS reads
        int sRow  = cr - r0;        // LDS row for dy=0 (holds global row cr-2)

        float S0 = 0.f, S1 = 0.f, S2 = 0.f, S3 = 0.f;
        #pragma unroll
        for (int dy = 0; dy < 5; ++dy) {
            const float* row = &lds[(sRow + dy) * ST + base];
            float rv[8];
            #pragma unroll
            for (int t = 0; t < 8; ++t) rv[t] = row[t];
            #pragma unroll
            for (int dx = 0; dx < 5; ++dx) {
                float kv = kw[dy * 5 + dx];
                S0 = fmaf(kv, rv[dx + 0], S0);
                S1 = fmaf(kv, rv[dx + 1], S1);
                S2 = fmaf(kv, rv[dx + 2], S2);
                S3 = fmaf(kv, rv[dx + 3], S3);
            }
        }

        // x^p at the 4 output positions (aligned float4)
        const float4 xp4 = *(const float4*)(&lds[(lr + 2) * ST + w0]);
        const float xv[4] = {xp4.x, xp4.y, xp4.z, xp4.w};

        float res[4];
        #pragma unroll
        for (int j = 0; j < 4; ++j) {
            int wj  = w0 + j;
            int cwj = wj < 2 ? 2 : (wj > 109 ? 109 : wj);
            int off = cwj - cwmin;  // == j for interior groups
            float s_ = off == 0 ? S0 : off == 1 ? S1 : off == 2 ? S2 : S3;
            res[j] = fmaf(wc * xv[j], __builtin_amdgcn_rcpf(sp + s_), bc);
        }
        float4 o = {res[0], res[1], res[2], res[3]};
        *(float4*)(oplane + r * Ww + w0) = o;
    }
}

extern "C" void kernel_launch(void* const* d_in, const int* in_sizes, int n_in,
                              void* d_out, int out_size, void* d_ws, size_t ws_size,
                              hipStream_t stream) {
    const float* x          = (const float*)d_in[0];
    const float* sigma      = (const float*)d_in[1];
    const float* pow_p      = (const float*)d_in[2];
    const float* sum_kernel = (const float*)d_in[3];
    const float* weight     = (const float*)d_in[4];
    const float* bias       = (const float*)d_in[5];
    float* out = (float*)d_out;

    dim3 grid(4, Cch, 32);   // (row tiles, C, B)
    dim3 block(256);
    bionorm_kernel<<<grid, block, 0, stream>>>(x, sigma, pow_p, sum_kernel,
                                               weight, bias, out);
}